// Round 9
// baseline (2933.977 us; speedup 1.0000x reference)
//
#include <hip/hip_runtime.h>
#include <hip/hip_bf16.h>

#define BB 256   // batch
#define SS 512   // seq len
#define II 128   // input size
#define HH 256   // hidden size

typedef __attribute__((ext_vector_type(8))) __bf16 bf16x8;
typedef __attribute__((ext_vector_type(4))) float f32x4;

__device__ __forceinline__ unsigned short f2bf(float f) {
    unsigned u = __float_as_uint(f);
    unsigned r = u + 0x7fffu + ((u >> 16) & 1u);
    return (unsigned short)(r >> 16);
}

// ---------------------------------------------------------------------------
// Weight repack (unchanged): fp32 [4H x K] -> bf16 MFMA B-fragment chains.
// ---------------------------------------------------------------------------
__global__ void pack_w_kernel(const float* __restrict__ Wih,
                              const float* __restrict__ Whh,
                              unsigned short* __restrict__ wp,
                              int Kin, int nkc) {
    int idx = blockIdx.x * blockDim.x + threadIdx.x;
    int total = 64 * nkc * 64;
    if (idx >= total) return;
    int nblk = idx / (nkc * 64);
    int rem  = idx % (nkc * 64);
    int kc = rem >> 6;
    int L  = rem & 63;
    int p  = nblk * 16 + (L & 15);
    int s  = p >> 6;
    int q6 = p & 63;
    int nw = q6 >> 5;
    int nb = (q6 >> 4) & 1;
    int c  = q6 & 15;
    int gam = nb * 2 + (c >> 3);            // 0:i 1:f 2:g 3:o
    int u   = s * 16 + nw * 8 + (c & 7);
    int srow = gam * HH + u;
    int k0 = kc * 32 + (L >> 4) * 8;
    unsigned short* dst = wp + (size_t)idx * 8;
    for (int j = 0; j < 8; ++j) {
        int k = k0 + j;
        float v = (k < Kin) ? Wih[(size_t)srow * Kin + k]
                            : Whh[(size_t)srow * HH + (k - Kin)];
        dst[j] = f2bf(v);
    }
}

__global__ void pack_bias_kernel(const float* bi0, const float* bh0,
                                 const float* bi1, const float* bh1,
                                 float* __restrict__ biasP) {
    int p = blockIdx.x * blockDim.x + threadIdx.x;
    if (p >= 2048) return;
    int layer = p >> 10;
    int pp = p & 1023;
    int s  = pp >> 6;
    int q6 = pp & 63;
    int nw = q6 >> 5;
    int nb = (q6 >> 4) & 1;
    int c  = q6 & 15;
    int gam = nb * 2 + (c >> 3);
    int u   = s * 16 + nw * 8 + (c & 7);
    int r = gam * HH + u;
    biasP[p] = layer ? (bi1[r] + bh1[r]) : (bi0[r] + bh0[r]);
}

// ---------------------------------------------------------------------------
// R6 epoch-slot wait (kept ONLY for layer 1's h1 ring, which is reused and
// therefore cannot use the sentinel trick).
// ---------------------------------------------------------------------------
__device__ __forceinline__ bool wait_slots(unsigned int* p, unsigned tgt) {
    long it = 0;
    for (;;) {
        unsigned v = __hip_atomic_load(p, __ATOMIC_RELAXED, __HIP_MEMORY_SCOPE_AGENT);
        if (__all((int)(v >= tgt))) return true;
        __builtin_amdgcn_s_sleep(1);
        if (++it > 2000000l) return false;   // safety bailout: no hangs
    }
}

// ---------------------------------------------------------------------------
// R7 sentinel poll-gather: Y0 is pre-filled with 0xFF bytes (bf16 0xFFFF =
// NaN, unreachable: h = o*tanh(c) is finite, f2bf of a finite float never
// yields 0xFFFF).  Each 4B word of Y0 is written atomically by exactly ONE
// producer swap (a packed unit-pair), so word != 0xFFFFFFFF <=> word final.
// Consumers poll their gather target directly: readiness travels WITH the
// data — one LLC round-trip replaces R6's {slot publish + slot poll +
// gather} (3 round-trips).  Producer h0 swaps become NON-returning
// fire-and-forget (no flag to order against; in-flight transients are
// absorbed by the retry loop).  Torn u64 reads are safe: each 4B half is
// checked independently.
// ---------------------------------------------------------------------------
__device__ __forceinline__ void poll_gather(unsigned long long* sp, int c8,
                                            unsigned long long* v,
                                            int* abort_flag) {
    long it = 0;
    for (;;) {
#pragma unroll
        for (int j = 0; j < 8; ++j)
            v[j] = __hip_atomic_load(sp + c8 + 8 * j, __ATOMIC_RELAXED,
                                     __HIP_MEMORY_SCOPE_AGENT);
        unsigned ok = 1u;
#pragma unroll
        for (int j = 0; j < 8; ++j)
            ok &= ((unsigned)v[j] != 0xFFFFFFFFu) &
                  ((unsigned)(v[j] >> 32) != 0xFFFFFFFFu);
        if (__all((int)ok)) return;
        __builtin_amdgcn_s_sleep(1);
        if (++it > 1000000l) { *abort_flag = 1; return; }   // no hangs
    }
}

// ---------------------------------------------------------------------------
// Persistent 2-layer LSTM. 256 WGs x 256 thr, 1 WG/CU.
// Coherence protocol R7:
//   - Y0 (h0 ring, write-once per t): sentinel poll-gather (above).  L0
//     publishes with non-returning relaxed agent swaps; NO slot, NO drain.
//     L0 is down to 2 barriers/step and zero tid0 serial work.
//   - Y1 (h1 ring, 4-deep, reused): R6 protocol — returning swaps (consumed
//     result => vmcnt retires on LLC reply), drain barrier, tid0 epoch-slot
//     exchange; consumers slot-poll then plain-gather.
//   - consumer loads relaxed agent atomics only, NO acquire fence (R1).
// ---------------------------------------------------------------------------
template <int LAYER>
__device__ __forceinline__ void run_layer(
    int bid, const float* __restrict__ x,
    const unsigned short* __restrict__ wp,
    const float* __restrict__ biasP,
    unsigned short* __restrict__ Y0,
    unsigned short* __restrict__ Y1,
    unsigned int* __restrict__ slots,
    float* __restrict__ out,
    unsigned short* As, int* abort_flag) {

    constexpr int KIN = LAYER ? HH : II;
    constexpr int KC  = KIN + HH;        // 384 / 512
    constexpr int NKC = KC >> 5;         // 12 / 16
    constexpr int KCP = KC + 8;          // A-row stride offset: 8 shorts

    const int g = (bid >> 4) & 7;
    const int s = bid & 15;
    const int tid = threadIdx.x;
    const int L = tid & 63;
    const int w = tid >> 6;
    const int mw = w & 1;
    const int nwv = w >> 1;
    const int c = L & 15;
    const int b0 = g * 32;

    // ---- persistent weight fragments (VGPR/AGPR file) ----
    const unsigned short* wB0 = wp + ((size_t)((s * 4 + nwv * 2 + 0) * NKC) * 64 + L) * 8;
    const unsigned short* wB1 = wp + ((size_t)((s * 4 + nwv * 2 + 1) * NKC) * 64 + L) * 8;
    bf16x8 w0r[NKC], w1r[NKC];
#pragma unroll
    for (int kc = 0; kc < NKC; ++kc) {
        w0r[kc] = *(const bf16x8*)(wB0 + (size_t)kc * 512);
        w1r[kc] = *(const bf16x8*)(wB1 + (size_t)kc * 512);
    }
    const float bq0 = biasP[LAYER * 1024 + s * 64 + nwv * 32 + c];
    const float bq1 = biasP[LAYER * 1024 + s * 64 + nwv * 32 + 16 + c];

    float cst[4] = {0.f, 0.f, 0.f, 0.f};

    float* outY  = out;
    float* outHn = out + (size_t)BB * SS * HH;
    float* outCn = outHn + (size_t)BB * HH;
    unsigned long long* Y0l = (unsigned long long*)Y0;   // 64 u64 per 256-unit row
    unsigned long long* Y1l = (unsigned long long*)Y1;
    unsigned int* Y0u = (unsigned int*)Y0;
    unsigned int* Y1u = (unsigned int*)Y1;

    // ---- layer-1 epoch slots (128B stride), only slotsG1 used in R7 ----
    unsigned int* slotsG1 = slots + (size_t)((1 * 8 + g) * 16) * 32;
    unsigned int* myslot  = slotsG1 + s * 32;

    // staging geometry: one batch row per 8 threads, 8 x u64 per thread
    const int row8 = tid >> 3;        // 0..31
    const int c8   = tid & 7;         // u64 col base; cols c8 + 8j, j=0..7
    // x staging (layer0): float4 rows rowb+8k, col cc
    const int rowb = tid >> 5;
    const int cc   = tid & 31;

    for (int t = 0; t < SS; ++t) {
        unsigned long long yv[8];     // layer1: y0[t] staged regs
        unsigned long long hv[8];
        float4 xv[4];                 // layer0: x[t]

        if (LAYER == 0) {
            // ---- issue x loads first: latency hides under the h poll ----
#pragma unroll
            for (int k = 0; k < 4; ++k) {
                int row = rowb + 8 * k;
                xv[k] = *(const float4*)(x + ((size_t)(b0 + row) * SS + t) * II + cc * 4);
            }
            // ---- h0[t-1]: sentinel poll-gather (readiness == data) ----
            if (t > 0) {
                poll_gather(Y0l + ((size_t)(t - 1) * BB + b0 + row8) * 64,
                            c8, hv, abort_flag);
            } else {
#pragma unroll
                for (int j = 0; j < 8; ++j) hv[j] = 0ull;
            }
            // ---- write A = [x | h_prev] to LDS ----
#pragma unroll
            for (int k = 0; k < 4; ++k) {
                int row = rowb + 8 * k;
                ushort4 pk;
                pk.x = f2bf(xv[k].x); pk.y = f2bf(xv[k].y);
                pk.z = f2bf(xv[k].z); pk.w = f2bf(xv[k].w);
                *(ushort4*)&As[row * KCP + cc * 4] = pk;
            }
#pragma unroll
            for (int j = 0; j < 8; ++j)
                *(unsigned long long*)&As[row8 * KCP + KIN + (c8 + 8 * j) * 4] = hv[j];
            __syncthreads();
            if (*abort_flag) return;
        } else {
            // ---- y0[t]: sentinel poll-gather (replaces slot wait) ----
            poll_gather(Y0l + ((size_t)t * BB + b0 + row8) * 64,
                        c8, yv, abort_flag);
            // ---- peers' h1[t-1]: slot wait (ring reuse => R6 protocol) ----
            if (w == 0 && t > 0) {
                if (!wait_slots(slotsG1 + (L & 15) * 32, (unsigned)t))
                    *abort_flag = 1;
            }
            __syncthreads();
            if (*abort_flag) return;
            // ---- h1[t-1] gather (slot-gated, plain agent atomics) ----
            if (t > 0) {
                unsigned long long* sp = Y1l + ((size_t)((t - 1) & 3) * BB + b0 + row8) * 64;
#pragma unroll
                for (int j = 0; j < 8; ++j)
                    hv[j] = __hip_atomic_load(sp + c8 + 8 * j, __ATOMIC_RELAXED,
                                              __HIP_MEMORY_SCOPE_AGENT);
            } else {
#pragma unroll
                for (int j = 0; j < 8; ++j) hv[j] = 0ull;
            }
            // ---- write A = [y0 | h1_prev] to LDS ----
#pragma unroll
            for (int j = 0; j < 8; ++j)
                *(unsigned long long*)&As[row8 * KCP + (c8 + 8 * j) * 4] = yv[j];
#pragma unroll
            for (int j = 0; j < 8; ++j)
                *(unsigned long long*)&As[row8 * KCP + KIN + (c8 + 8 * j) * 4] = hv[j];
            __syncthreads();
        }

        // ---- GEMM: gates[32 x 64] = A[32 x KC] * W^T ----
        f32x4 acc0 = {0.f, 0.f, 0.f, 0.f};
        f32x4 acc1 = {0.f, 0.f, 0.f, 0.f};
        const unsigned short* aBase = &As[(mw * 16 + c) * KCP + (L >> 4) * 8];
#pragma unroll
        for (int kc = 0; kc < NKC; ++kc) {
            bf16x8 a = *(const bf16x8*)(aBase + kc * 32);
            acc0 = __builtin_amdgcn_mfma_f32_16x16x32_bf16(a, w0r[kc], acc0, 0, 0, 0);
            acc1 = __builtin_amdgcn_mfma_f32_16x16x32_bf16(a, w1r[kc], acc1, 0, 0, 0);
        }
        __syncthreads();   // As-reuse guard: all reads done before next step's writes

        // ---- epilogue: acc0 = i|f, acc1 = g|o (partner lane L^8) ----
#pragma unroll
        for (int r = 0; r < 4; ++r) {
            float x0 = acc0[r] + bq0;
            float x1 = acc1[r] + bq1;
            float y0v = __shfl_xor(x0, 8, 64);
            float y1v = __shfl_xor(x1, 8, 64);
            bool lo = (L & 8) == 0;
            float iv = lo ? x0 : y0v;
            float fv = lo ? y0v : x0;
            float gv = lo ? x1 : y1v;
            float ov = lo ? y1v : x1;
            iv = 1.f / (1.f + __expf(-iv));
            fv = 1.f / (1.f + __expf(-fv));
            ov = 1.f / (1.f + __expf(-ov));
            gv = 1.f - 2.f / (1.f + __expf(2.f * gv));
            float cn = fv * cst[r] + iv * gv;
            cst[r] = cn;
            float tc = 1.f - 2.f / (1.f + __expf(2.f * cn));
            float hn = ov * tc;

            int brow = b0 + mw * 16 + ((L >> 4) << 2) + r;
            int hu = s * 16 + nwv * 8 + (L & 7);
            // pack 2 adjacent units (lane pair L, L^1) into one 4B swap
            unsigned hb = (unsigned)f2bf(hn);
            unsigned pb = (unsigned)__shfl_xor((int)hb, 1, 64);
            unsigned packed = hb | (pb << 16);
            if (lo && (L & 1) == 0) {
                if (LAYER == 0) {
                    // non-returning fire-and-forget: sentinel poll absorbs
                    // any in-flight transient; no ordering needed
                    size_t di = (((size_t)t * BB + brow) * HH + hu) >> 1;
                    (void)__hip_atomic_exchange(Y0u + di, packed,
                                                __ATOMIC_RELAXED,
                                                __HIP_MEMORY_SCOPE_AGENT);
                } else {
                    // returning swap: vmcnt retires on LLC reply => drain
                    // barrier below orders data before the slot publish
                    size_t di = (((size_t)(t & 3) * BB + brow) * HH + hu) >> 1;
                    unsigned old = __hip_atomic_exchange(Y1u + di, packed,
                                                         __ATOMIC_RELAXED,
                                                         __HIP_MEMORY_SCOPE_AGENT);
                    asm volatile("" :: "v"(old));
                }
            }
            if (LAYER == 1 && lo) {
                outY[((size_t)brow * SS + t) * HH + hu] = hn;
                if (t == SS - 1) {
                    outHn[brow * HH + hu] = hn;
                    outCn[brow * HH + hu] = cn;
                }
            }
        }

        if (LAYER == 1) {
            __syncthreads();  // vmcnt(0): all returning swaps ack'd BY THE LLC
            if (tid == 0) {
                unsigned old = __hip_atomic_exchange(myslot, (unsigned)(t + 1),
                                                     __ATOMIC_RELAXED,
                                                     __HIP_MEMORY_SCOPE_AGENT);
                asm volatile("" :: "v"(old));
            }
        }
        // LAYER 0: no end barrier, no slot — swaps drain in flight while the
        // next step's x prefetch + poll proceed.
    }
}

__global__ __launch_bounds__(256, 1) void lstm_main(
    const float* __restrict__ x,
    const unsigned short* __restrict__ wp0,
    const unsigned short* __restrict__ wp1,
    const float* __restrict__ biasP,
    unsigned short* __restrict__ Y0,
    unsigned short* __restrict__ Y1,
    unsigned int* __restrict__ slots,
    float* __restrict__ out) {

    __shared__ unsigned short As[32 * 520];
    __shared__ int abort_flag;
    if (threadIdx.x == 0) abort_flag = 0;
    __syncthreads();

    int bid = blockIdx.x;
    if (bid < 128)
        run_layer<0>(bid, x, wp0, biasP, Y0, Y1, slots, out, As, &abort_flag);
    else
        run_layer<1>(bid, x, wp1, biasP, Y0, Y1, slots, out, As, &abort_flag);
}

extern "C" void kernel_launch(void* const* d_in, const int* in_sizes, int n_in,
                              void* d_out, int out_size, void* d_ws, size_t ws_size,
                              hipStream_t stream) {
    const float* x    = (const float*)d_in[0];
    const float* Wih0 = (const float*)d_in[1];
    const float* Whh0 = (const float*)d_in[2];
    const float* bih0 = (const float*)d_in[3];
    const float* bhh0 = (const float*)d_in[4];
    const float* Wih1 = (const float*)d_in[5];
    const float* Whh1 = (const float*)d_in[6];
    const float* bih1 = (const float*)d_in[7];
    const float* bhh1 = (const float*)d_in[8];

    char* ws = (char*)d_ws;
    size_t o = 0;
    unsigned short* wp0 = (unsigned short*)(ws + o); o += (size_t)64 * 12 * 512 * 2;  // 768 KB
    unsigned short* wp1 = (unsigned short*)(ws + o); o += (size_t)64 * 16 * 512 * 2;  // 1 MB
    float* biasP = (float*)(ws + o);                 o += 2048 * 4;
    unsigned short* Y0 = (unsigned short*)(ws + o);  o += (size_t)SS * BB * HH * 2;   // 67 MB
    unsigned short* Y1 = (unsigned short*)(ws + o);  o += (size_t)4 * BB * HH * 2;    // 512 KB
    unsigned int* slots = (unsigned int*)(ws + o);   o += (size_t)2 * 8 * 16 * 32 * 4; // 16 KB

    // R7: sentinel-fill Y0 (0xFF bytes = bf16 NaN, unreachable by finite h)
    hipMemsetAsync(Y0, 0xFF, (size_t)SS * BB * HH * 2, stream);
    hipMemsetAsync(slots, 0, (size_t)2 * 8 * 16 * 32 * 4, stream);
    pack_w_kernel<<<192, 256, 0, stream>>>(Wih0, Whh0, wp0, II, 12);
    pack_w_kernel<<<256, 256, 0, stream>>>(Wih1, Whh1, wp1, HH, 16);
    pack_bias_kernel<<<8, 256, 0, stream>>>(bih0, bhh0, bih1, bhh1, biasP);
    lstm_main<<<256, 256, 0, stream>>>(x, wp0, wp1, biasP, Y0, Y1, slots, (float*)d_out);
}